// Round 16
// baseline (140.704 us; speedup 1.0000x reference)
//
#include <hip/hip_runtime.h>
#include <math.h>

#define BATCH 32
#define TLEN 8192
#define NCH 128          // chunks
#define CLEN 64          // steps per chunk
#define SUBL 8           // steps per sub-chunk
#define NSUB 8           // sub-chunks per chunk
#define NROWS (BATCH*TLEN)   // 262144 rows

typedef _Float16 h2 __attribute__((ext_vector_type(2)));
union HU { unsigned int u; h2 h; };
__device__ __forceinline__ h2 u2h(unsigned int x) { HU t; t.u = x; return t.h; }
__device__ __forceinline__ unsigned int pkh(float a, float b) {
    HU t; t.h = h2{(_Float16)a, (_Float16)b}; return t.u;
}

#if __has_builtin(__builtin_amdgcn_fdot2)
__device__ __forceinline__ float dot2f(h2 a, h2 b, float c) {
    return __builtin_amdgcn_fdot2(a, b, c, false);
}
#else
__device__ __forceinline__ float dot2f(h2 a, h2 b, float c) {
    return fmaf((float)a.x, (float)b.x, fmaf((float)a.y, (float)b.y, c));
}
#endif

// ---------------------------------------------------------------------------
// HiPPO step, tree-form prefix: s <- (I - A/t) s + (x/t) * r
// ---------------------------------------------------------------------------
__device__ __forceinline__ void hippo_step(float s[8], float inv_t, float xb) {
    const float R[8] = {1.0f, 1.7320508075688772f, 2.23606797749979f,
                        2.6457513110645907f, 3.0f, 3.3166247903554f,
                        3.605551275463989f, 3.872983346207417f};
    float q0 = R[0]*s[0], q1 = R[1]*s[1], q2 = R[2]*s[2], q3 = R[3]*s[3];
    float q4 = R[4]*s[4], q5 = R[5]*s[5], q6 = R[6]*s[6];
    float t01 = q0+q1, t23 = q2+q3, t45 = q4+q5;
    float p1 = q0, p2 = t01, p3 = t01+q2, p4 = t01+t23;
    float p5 = p4+q4, p6 = p4+t45, p7 = p6+q6;
    float p[8] = {0.0f, p1, p2, p3, p4, p5, p6, p7};
    #pragma unroll
    for (int n = 0; n < 8; n++) {
        float as = fmaf(R[n], p[n], (float)(n + 1) * s[n]);
        s[n] = fmaf(-inv_t, as, fmaf(xb, R[n], s[n]));
    }
}

// ---------------------------------------------------------------------------
// Kernel A: per-chunk runs (CLEN=64) with 8-wide batched + prefetched x loads.
// ---------------------------------------------------------------------------
__global__ void hippo_chunk_kernel(const float* __restrict__ x_seq,
                                   float* __restrict__ Psub,  // [NCH][NSUB][8][8]
                                   float* __restrict__ Vsub,  // [NCH][NSUB][64][8]
                                   float* __restrict__ Pfin,  // [NCH][8][8]
                                   float* __restrict__ Vfin)  // [NCH][64][8]
{
    int chunk = blockIdx.x;
    int tid = threadIdx.x;
    if (tid >= 72) return;
    bool isP = tid >= 64;
    int col = tid - 64;
    int b = tid >> 1, c = tid & 1;

    float s[8];
    #pragma unroll
    for (int n = 0; n < 8; n++) s[n] = (isP && n == col) ? 1.0f : 0.0f;

    int t0c = chunk * CLEN;
    size_t xbase = ((size_t)b * TLEN + t0c) * 2 + c;

    float xl[8];
    #pragma unroll
    for (int k = 0; k < 8; k++)
        xl[k] = isP ? 0.0f : x_seq[xbase + 2 * k];

    #pragma unroll 1
    for (int ii = 0; ii < CLEN; ii += 8) {
        int sub = ii >> 3;
        if (isP) {
            #pragma unroll
            for (int n = 0; n < 8; n++)
                Psub[(((size_t)chunk * NSUB + sub) * 8 + n) * 8 + col] = s[n];
        } else {
            #pragma unroll
            for (int n = 0; n < 8; n++)
                Vsub[(((size_t)chunk * NSUB + sub) * 64 + tid) * 8 + n] = s[n];
        }
        float xn8[8];
        bool more = (ii + 8 < CLEN) && !isP;
        #pragma unroll
        for (int k = 0; k < 8; k++)
            xn8[k] = more ? x_seq[xbase + 2 * (ii + 8 + k)] : 0.0f;

        #pragma unroll
        for (int k = 0; k < 8; k++) {
            float tf = (float)(t0c + ii + k + 1);
            float inv_t = 1.0f / tf;
            hippo_step(s, inv_t, xl[k] * inv_t);
        }
        #pragma unroll
        for (int k = 0; k < 8; k++) xl[k] = xn8[k];
    }
    if (isP) {
        #pragma unroll
        for (int n = 0; n < 8; n++) Pfin[((size_t)chunk * 8 + n) * 8 + col] = s[n];
    } else {
        #pragma unroll
        for (int n = 0; n < 8; n++) Vfin[((size_t)chunk * 64 + tid) * 8 + n] = s[n];
    }
}

// ---------------------------------------------------------------------------
// KAN helpers
// ---------------------------------------------------------------------------
__device__ __forceinline__ void bspline4(float x, float& B0, float& B1,
                                         float& B2, float& B3, int& m)
{
    float tt = fmaf(x, 5.0f, 8.0f);        // (x + 1.6) * 5
    float fm = floorf(tt);
    float u = tt - fm;
    bool valid = (fm >= 0.0f) && (fm <= 15.0f);
    float u2 = u * u, u3 = u2 * u;
    float um = 1.0f - u;
    B0 = um * um * um * (1.0f / 6.0f);
    B3 = u3 * (1.0f / 6.0f);
    B1 = fmaf(3.0f, u3, fmaf(-6.0f, u2, 4.0f)) * (1.0f / 6.0f);
    B2 = fmaf(-3.0f, u3, fmaf(3.0f, u2, fmaf(3.0f, u, 1.0f))) * (1.0f / 6.0f);
    float msk = valid ? 1.0f : 0.0f;
    B0 *= msk; B1 *= msk; B2 *= msk; B3 *= msk;
    m = valid ? (int)fm : 0;
}

__device__ __forceinline__ float silu(float x) {
    return x / (1.0f + __expf(-x));
}

// FUSED COMPOSE + EXPAND + KAN (2-launch pipeline):
//  wave 0: lanes 0-15 walk the chunk-prefix for this block's 2 seqs (shfl w8,
//          bitwise-identical to the old compose kernel) -> sS0 (LDS);
//          lanes 0-63 then expand 32 sub-chunks x 2c -> hbuf.  All wave-0
//          internal: no barrier needed between walk and expand.
//  waves 1-3 (tid 64-255): stage phase-1 weights concurrently (grid-stride).
// hbuf rot = ((row>>3) ^ (row>>6)) & 7: breaks the r15 4-way write collision
// between uc and uc+8. LDS 48384 B -> 3 blocks/CU.
__global__ __launch_bounds__(256) void kan_kernel(
    const float* __restrict__ x_seq,
    const float* __restrict__ Psub,
    const float* __restrict__ Vsub,
    const float* __restrict__ Pfin,
    const float* __restrict__ Vfin,
    const float* __restrict__ wb1, const float* __restrict__ ws1,
    const float* __restrict__ wb2, const float* __restrict__ ws2,
    const float* __restrict__ wb3, const float* __restrict__ ws3,
    float* __restrict__ out)
{
    __shared__ unsigned int wldsU[9728];     // 38912 B weights
    __shared__ unsigned int hbuf[256 * 9];   //  9216 B activations
    __shared__ float sS0[64];                //   256 B chunk-start states
    int tid = threadIdx.x;
    int b = blockIdx.x >> 5;                 // 0..31
    int tseg = blockIdx.x & 31;              // 0..31
    int row = blockIdx.x * 256 + tid;
    int rot = ((tid >> 3) ^ (tid >> 6)) & 7;

    if (tid < 64) {
        // ---- wave 0 part 1: prefix walk (lanes 0-15)
        if (tid < 16) {
            int sl = tid >> 3;               // seq_local 0,1
            int n = tid & 7;
            int seq = b * 2 + sl;
            int c0 = tseg * 4;
            float cur = 0.0f;
            #pragma unroll 1
            for (int ck = 0; ck < NCH; ck++) {
                if (ck >= c0) {
                    sS0[(ck - c0) * 16 + tid] = cur;
                    if (ck == c0 + 3) break;
                }
                float acc = Vfin[((size_t)ck * 64 + seq) * 8 + n];
                float pr[8];
                #pragma unroll
                for (int m = 0; m < 8; m++) pr[m] = Pfin[(ck * 8 + n) * 8 + m];
                #pragma unroll
                for (int m = 0; m < 8; m++)
                    acc = fmaf(pr[m], __shfl(cur, m, 8), acc);
                cur = acc;
            }
        }
        // ---- wave 0 part 2: expand 32 sub-chunks x 2c (lanes 0-63; same
        // wave as the walk -> LDS program order guarantees sS0 visibility)
        {
            int uc = tid >> 1;               // 0..31
            int c = tid & 1;
            int chunk = (tseg << 2) + (uc >> 3);
            int chunk_loc = uc >> 3;
            int sub = uc & 7;
            int seq = b * 2 + c;
            int row_loc = uc << 3;
            int wrot = (uc ^ (uc >> 3)) & 7;

            float s0v[8];
            #pragma unroll
            for (int n = 0; n < 8; n++)
                s0v[n] = sS0[chunk_loc * 16 + c * 8 + n];

            const float* Pp = &Psub[((size_t)chunk * NSUB + sub) * 64];
            const float* Vp = &Vsub[(((size_t)chunk * NSUB + sub) * 64 + seq) * 8];

            float s[8];
            #pragma unroll
            for (int n = 0; n < 8; n++) {
                float acc = Vp[n];
                #pragma unroll
                for (int m = 0; m < 8; m++)
                    acc = fmaf(Pp[n * 8 + m], s0v[m], acc);
                s[n] = acc;
            }

            int t0 = chunk * CLEN + sub * SUBL;
            float xv8[8];
            #pragma unroll
            for (int k = 0; k < 8; k++)
                xv8[k] = x_seq[((size_t)b * TLEN + t0 + k) * 2 + c];

            #pragma unroll
            for (int i = 0; i < SUBL; i++) {
                float tf = (float)(t0 + i + 1);
                float inv_t = 1.0f / tf;
                hippo_step(s, inv_t, xv8[i] * inv_t);
                #pragma unroll
                for (int k = 0; k < 4; k++)
                    hbuf[(row_loc + i) * 9 + ((c * 4 + k + wrot) & 7)] =
                        pkh(s[2 * k], s[2 * k + 1]);
            }
        }
    } else {
        // ---- waves 1-3: stage phase-1 weights (grid-stride over 512 edges)
        #pragma unroll 1
        for (int e = tid - 64; e < 512; e += 192) {
            int i = e >> 5, o = e & 31;
            const float* src = ws1 + o * 208 + i * 13;
            int dst = i * 608 + o * 19;
            #pragma unroll
            for (int p = 0; p < 19; p++) {
                int j0 = (p < 10) ? (2 * p) : (2 * (p - 10) + 1);
                float lo = (j0 >= 3 && j0 <= 15) ? src[j0 - 3] : 0.0f;
                float hi = (j0 + 1 >= 3 && j0 + 1 <= 15) ? src[j0 - 2] : 0.0f;
                wldsU[dst + p] = pkh(lo, hi);
            }
        }
    }
    __syncthreads();

    // ---- layer 1: 16 -> 32 (rolled over 8 input pairs from hbuf)
    float acc1[32];
    #pragma unroll
    for (int o = 0; o < 32; o++) acc1[o] = 0.0f;

    #pragma unroll 1
    for (int pi = 0; pi < 8; pi++) {
        h2 xp = u2h(hbuf[tid * 9 + ((pi + rot) & 7)]);
        #pragma unroll
        for (int par = 0; par < 2; par++) {
            int i = 2 * pi + par;
            float xv = (par == 0) ? (float)xp.x : (float)xp.y;
            float sx = silu(xv);
            float B0, B1, B2, B3; int m;
            bspline4(xv, B0, B1, B2, B3, m);
            h2 B01 = u2h(pkh(B0, B1));
            h2 B23 = u2h(pkh(B2, B3));
            int poff = (m & 1) ? (10 + ((m - 1) >> 1)) : (m >> 1);
            int base = i * 608 + poff;
            const float* wbrow = wb1 + i;       // wb1[o*16+i]
            #pragma unroll
            for (int o = 0; o < 32; o++) {
                unsigned int da = wldsU[base + o * 19];
                unsigned int db = wldsU[base + o * 19 + 1];
                float a = acc1[o];
                a = dot2f(B01, u2h(da), a);
                a = dot2f(B23, u2h(db), a);
                a = fmaf(sx, wbrow[o * 16], a);
                acc1[o] = a;
            }
        }
    }
    // first half of layer-1 output -> own hbuf row
    #pragma unroll
    for (int op = 0; op < 8; op++)
        hbuf[tid * 9 + ((op + rot) & 7)] = pkh(acc1[2 * op], acc1[2 * op + 1]);

    __syncthreads();   // all waves done reading phase-1 weights

    // ---- stage phase 2 (affine, all threads)
    {
        int i = tid >> 3, q = tid & 7;
        #pragma unroll
        for (int oo = 0; oo < 2; oo++) {
            int o = q + oo * 8;
            const float* src = ws2 + o * 416 + i * 13;
            int dst = i * 304 + o * 19;
            #pragma unroll
            for (int p = 0; p < 19; p++) {
                int j0 = (p < 10) ? (2 * p) : (2 * (p - 10) + 1);
                float lo = (j0 >= 3 && j0 <= 15) ? src[j0 - 3] : 0.0f;
                float hi = (j0 + 1 >= 3 && j0 + 1 <= 15) ? src[j0 - 2] : 0.0f;
                wldsU[dst + p] = pkh(lo, hi);
            }
        }
    }
    __syncthreads();

    // ---- layer 2: 32 -> 16 in two input halves (acc1[16..31] in regs
    // through half 0; written to own row between halves)
    float acc2[16];
    #pragma unroll
    for (int o = 0; o < 16; o++) acc2[o] = 0.0f;

    #pragma unroll 1
    for (int half = 0; half < 2; half++) {
        #pragma unroll 1
        for (int pi = 0; pi < 8; pi++) {
            h2 yp = u2h(hbuf[tid * 9 + ((pi + rot) & 7)]);
            #pragma unroll
            for (int par = 0; par < 2; par++) {
                int i = half * 16 + 2 * pi + par;
                float yv = (par == 0) ? (float)yp.x : (float)yp.y;
                float sx = silu(yv);
                float B0, B1, B2, B3; int m;
                bspline4(yv, B0, B1, B2, B3, m);
                h2 B01 = u2h(pkh(B0, B1));
                h2 B23 = u2h(pkh(B2, B3));
                int poff = (m & 1) ? (10 + ((m - 1) >> 1)) : (m >> 1);
                int base = i * 304 + poff;
                const float* wbrow = wb2 + i;   // wb2[o*32+i]
                #pragma unroll
                for (int o = 0; o < 16; o++) {
                    unsigned int da = wldsU[base + o * 19];
                    unsigned int db = wldsU[base + o * 19 + 1];
                    float a = acc2[o];
                    a = dot2f(B01, u2h(da), a);
                    a = dot2f(B23, u2h(db), a);
                    a = fmaf(sx, wbrow[o * 32], a);
                    acc2[o] = a;
                }
            }
        }
        if (half == 0) {
            #pragma unroll
            for (int op = 0; op < 8; op++)
                hbuf[tid * 9 + ((op + rot) & 7)] =
                    pkh(acc1[16 + 2 * op], acc1[17 + 2 * op]);
        }
    }

    // ---- layer 3: 16 -> 1, fully unrolled, fp32 weights from global
    float acc3 = 0.0f;
    #pragma unroll
    for (int i = 0; i < 16; i++) {
        float xv = acc2[i];
        float sx = silu(xv);
        float B0, B1, B2, B3; int m;
        bspline4(xv, B0, B1, B2, B3, m);
        acc3 = fmaf(sx, wb3[i], acc3);
        const float* w3 = &ws3[i * 13];
        int j0 = m - 3;
        float w0v = (j0 >= 0)              ? w3[j0]     : 0.0f;
        float w1v = (j0 >= -1 && j0 <= 11) ? w3[j0 + 1] : 0.0f;
        float w2v = (j0 >= -2 && j0 <= 10) ? w3[j0 + 2] : 0.0f;
        float w3v = (j0 <= 9)              ? w3[j0 + 3] : 0.0f;
        acc3 = fmaf(B0, w0v, acc3);
        acc3 = fmaf(B1, w1v, acc3);
        acc3 = fmaf(B2, w2v, acc3);
        acc3 = fmaf(B3, w3v, acc3);
    }
    out[row] = acc3;
}

// ---------------------------------------------------------------------------
extern "C" void kernel_launch(void* const* d_in, const int* in_sizes, int n_in,
                              void* d_out, int out_size, void* d_ws, size_t ws_size,
                              hipStream_t stream) {
    const float* x_seq = (const float*)d_in[0];
    const float* wb1   = (const float*)d_in[1];
    const float* ws1   = (const float*)d_in[2];
    const float* wb2   = (const float*)d_in[3];
    const float* ws2   = (const float*)d_in[4];
    const float* wb3   = (const float*)d_in[5];
    const float* ws3   = (const float*)d_in[6];

    float* ws   = (float*)d_ws;
    float* Psub = ws;                   // 128*8*64        =   65536
    float* Vsub = ws + 65536;           // 128*8*64*8      =  524288
    float* Pfin = ws + 589824;          // 128*64          =    8192
    float* Vfin = ws + 598016;          // 128*64*8        =   65536
    float* out  = (float*)d_out;

    hipLaunchKernelGGL(hippo_chunk_kernel, dim3(NCH), dim3(128), 0, stream,
                       x_seq, Psub, Vsub, Pfin, Vfin);
    hipLaunchKernelGGL(kan_kernel, dim3(NROWS / 256), dim3(256), 0, stream,
                       x_seq, Psub, Vsub, Pfin, Vfin,
                       wb1, ws1, wb2, ws2, wb3, ws3, out);
}

// Round 17
// 121.344 us; speedup vs baseline: 1.1595x; 1.1595x over previous
//
#include <hip/hip_runtime.h>
#include <math.h>

#define BATCH 32
#define TLEN 8192
#define NCH 32           // chunks
#define CLEN 256         // steps per chunk
#define SUBL 8           // steps per sub-chunk
#define NSUB 32          // sub-chunks per chunk
#define NROWS (BATCH*TLEN)   // 262144 rows

typedef _Float16 h2 __attribute__((ext_vector_type(2)));
union HU { unsigned int u; h2 h; };
__device__ __forceinline__ h2 u2h(unsigned int x) { HU t; t.u = x; return t.h; }
__device__ __forceinline__ unsigned int pkh(float a, float b) {
    HU t; t.h = h2{(_Float16)a, (_Float16)b}; return t.u;
}

#if __has_builtin(__builtin_amdgcn_fdot2)
__device__ __forceinline__ float dot2f(h2 a, h2 b, float c) {
    return __builtin_amdgcn_fdot2(a, b, c, false);
}
#else
__device__ __forceinline__ float dot2f(h2 a, h2 b, float c) {
    return fmaf((float)a.x, (float)b.x, fmaf((float)a.y, (float)b.y, c));
}
#endif

// ---------------------------------------------------------------------------
// HiPPO step, tree-form prefix: s <- (I - A/t) s + (x/t) * r
// ---------------------------------------------------------------------------
__device__ __forceinline__ void hippo_step(float s[8], float inv_t, float xb) {
    const float R[8] = {1.0f, 1.7320508075688772f, 2.23606797749979f,
                        2.6457513110645907f, 3.0f, 3.3166247903554f,
                        3.605551275463989f, 3.872983346207417f};
    float q0 = R[0]*s[0], q1 = R[1]*s[1], q2 = R[2]*s[2], q3 = R[3]*s[3];
    float q4 = R[4]*s[4], q5 = R[5]*s[5], q6 = R[6]*s[6];
    float t01 = q0+q1, t23 = q2+q3, t45 = q4+q5;
    float p1 = q0, p2 = t01, p3 = t01+q2, p4 = t01+t23;
    float p5 = p4+q4, p6 = p4+t45, p7 = p6+q6;
    float p[8] = {0.0f, p1, p2, p3, p4, p5, p6, p7};
    #pragma unroll
    for (int n = 0; n < 8; n++) {
        float as = fmaf(R[n], p[n], (float)(n + 1) * s[n]);
        s[n] = fmaf(-inv_t, as, fmaf(xb, R[n], s[n]));
    }
}

// ---------------------------------------------------------------------------
// Kernel A: per-chunk runs (CLEN=256) with 8-wide batched + prefetched x loads.
// ---------------------------------------------------------------------------
__global__ void hippo_chunk_kernel(const float* __restrict__ x_seq,
                                   float* __restrict__ Psub,  // [NCH][NSUB][8][8]
                                   float* __restrict__ Vsub,  // [NCH][NSUB][64][8]
                                   float* __restrict__ Pfin,  // [NCH][8][8]
                                   float* __restrict__ Vfin)  // [NCH][64][8]
{
    int chunk = blockIdx.x;
    int tid = threadIdx.x;
    if (tid >= 72) return;
    bool isP = tid >= 64;
    int col = tid - 64;
    int b = tid >> 1, c = tid & 1;

    float s[8];
    #pragma unroll
    for (int n = 0; n < 8; n++) s[n] = (isP && n == col) ? 1.0f : 0.0f;

    int t0c = chunk * CLEN;
    size_t xbase = ((size_t)b * TLEN + t0c) * 2 + c;

    float xl[8];
    #pragma unroll
    for (int k = 0; k < 8; k++)
        xl[k] = isP ? 0.0f : x_seq[xbase + 2 * k];

    #pragma unroll 1
    for (int ii = 0; ii < CLEN; ii += 8) {
        int sub = ii >> 3;
        if (isP) {
            #pragma unroll
            for (int n = 0; n < 8; n++)
                Psub[(((size_t)chunk * NSUB + sub) * 8 + n) * 8 + col] = s[n];
        } else {
            #pragma unroll
            for (int n = 0; n < 8; n++)
                Vsub[(((size_t)chunk * NSUB + sub) * 64 + tid) * 8 + n] = s[n];
        }
        float xn8[8];
        bool more = (ii + 8 < CLEN) && !isP;
        #pragma unroll
        for (int k = 0; k < 8; k++)
            xn8[k] = more ? x_seq[xbase + 2 * (ii + 8 + k)] : 0.0f;

        #pragma unroll
        for (int k = 0; k < 8; k++) {
            float tf = (float)(t0c + ii + k + 1);
            float inv_t = 1.0f / tf;
            hippo_step(s, inv_t, xl[k] * inv_t);
        }
        #pragma unroll
        for (int k = 0; k < 8; k++) xl[k] = xn8[k];
    }
    if (isP) {
        #pragma unroll
        for (int n = 0; n < 8; n++) Pfin[((size_t)chunk * 8 + n) * 8 + col] = s[n];
    } else {
        #pragma unroll
        for (int n = 0; n < 8; n++) Vfin[((size_t)chunk * 64 + tid) * 8 + n] = s[n];
    }
}

// ---------------------------------------------------------------------------
// Kernel B: shfl-free compose, thread-per-seq. 32 iterations; states in
// registers; full 8x8 matvec per iteration (8 independent fma chains);
// next chunk's P/V explicitly prefetched. No cross-lane ops (r16 lesson:
// the shfl-chain version cost ~40us -- ds_bpermute latency x 8 x 128).
// ---------------------------------------------------------------------------
__global__ __launch_bounds__(64) void hippo_compose_kernel(
    const float* __restrict__ Pfin,
    const float* __restrict__ Vfin,
    float* __restrict__ S0)              // [NCH][64][8]
{
    int tid = threadIdx.x;               // seq 0..63
    float s[8];
    #pragma unroll
    for (int n = 0; n < 8; n++) s[n] = 0.0f;

    float P[64], v[8];
    #pragma unroll
    for (int k = 0; k < 64; k++) P[k] = Pfin[k];
    #pragma unroll
    for (int n = 0; n < 8; n++) v[n] = Vfin[tid * 8 + n];

    #pragma unroll 1
    for (int ck = 0; ck < NCH; ck++) {
        int nk = (ck + 1 < NCH) ? (ck + 1) : ck;
        float Pn[64], vn[8];
        #pragma unroll
        for (int k = 0; k < 64; k++) Pn[k] = Pfin[nk * 64 + k];
        #pragma unroll
        for (int n = 0; n < 8; n++) vn[n] = Vfin[(nk * 64 + tid) * 8 + n];

        #pragma unroll
        for (int n = 0; n < 8; n++) S0[((size_t)ck * 64 + tid) * 8 + n] = s[n];

        float ns[8];
        #pragma unroll
        for (int n = 0; n < 8; n++) {
            float acc = v[n];
            #pragma unroll
            for (int m = 0; m < 8; m++)
                acc = fmaf(P[n * 8 + m], s[m], acc);
            ns[n] = acc;
        }
        #pragma unroll
        for (int n = 0; n < 8; n++) s[n] = ns[n];
        #pragma unroll
        for (int k = 0; k < 64; k++) P[k] = Pn[k];
        #pragma unroll
        for (int n = 0; n < 8; n++) v[n] = vn[n];
    }
}

// ---------------------------------------------------------------------------
// KAN helpers
// ---------------------------------------------------------------------------
__device__ __forceinline__ void bspline4(float x, float& B0, float& B1,
                                         float& B2, float& B3, int& m)
{
    float tt = fmaf(x, 5.0f, 8.0f);        // (x + 1.6) * 5
    float fm = floorf(tt);
    float u = tt - fm;
    bool valid = (fm >= 0.0f) && (fm <= 15.0f);
    float u2 = u * u, u3 = u2 * u;
    float um = 1.0f - u;
    B0 = um * um * um * (1.0f / 6.0f);
    B3 = u3 * (1.0f / 6.0f);
    B1 = fmaf(3.0f, u3, fmaf(-6.0f, u2, 4.0f)) * (1.0f / 6.0f);
    B2 = fmaf(-3.0f, u3, fmaf(3.0f, u2, fmaf(3.0f, u, 1.0f))) * (1.0f / 6.0f);
    float msk = valid ? 1.0f : 0.0f;
    B0 *= msk; B1 *= msk; B2 *= msk; B3 *= msk;
    m = valid ? (int)fm : 0;
}

__device__ __forceinline__ float silu(float x) {
    return x / (1.0f + __expf(-x));
}

// FUSED EXPAND + KAN (r15 proven core, simpler mapping: chunk = tseg,
// sub = uc since CLEN=256 == rows per block). LDS 48128 B -> 3 blocks/CU.
__global__ __launch_bounds__(256) void kan_kernel(
    const float* __restrict__ x_seq,
    const float* __restrict__ Psub,
    const float* __restrict__ Vsub,
    const float* __restrict__ S0,
    const float* __restrict__ wb1, const float* __restrict__ ws1,
    const float* __restrict__ wb2, const float* __restrict__ ws2,
    const float* __restrict__ wb3, const float* __restrict__ ws3,
    float* __restrict__ out)
{
    __shared__ unsigned int wldsU[9728];     // 38912 B weights
    __shared__ unsigned int hbuf[256 * 9];   //  9216 B activations
    int tid = threadIdx.x;
    int b = blockIdx.x >> 5;                 // 0..31
    int tseg = blockIdx.x & 31;              // 0..31 == chunk
    int row = blockIdx.x * 256 + tid;
    int rot = ((tid >> 3) ^ (tid >> 6)) & 7;

    // ---- fused expand: 32 sub-chunks x 2 c -> hbuf rows (8 of 9 dwords/row)
    if (tid < 64) {
        int uc = tid >> 1;                   // 0..31 == sub
        int c = tid & 1;
        int chunk = tseg;
        int seq = b * 2 + c;
        int row_loc = uc << 3;
        int wrot = (uc ^ (uc >> 3)) & 7;

        float s0v[8];
        #pragma unroll
        for (int n = 0; n < 8; n++)
            s0v[n] = S0[((size_t)chunk * 64 + seq) * 8 + n];

        const float* Pp = &Psub[((size_t)chunk * NSUB + uc) * 64];
        const float* Vp = &Vsub[(((size_t)chunk * NSUB + uc) * 64 + seq) * 8];

        float s[8];
        #pragma unroll
        for (int n = 0; n < 8; n++) {
            float acc = Vp[n];
            #pragma unroll
            for (int m = 0; m < 8; m++)
                acc = fmaf(Pp[n * 8 + m], s0v[m], acc);
            s[n] = acc;
        }

        int t0 = chunk * CLEN + uc * SUBL;
        float xv8[8];
        #pragma unroll
        for (int k = 0; k < 8; k++)
            xv8[k] = x_seq[((size_t)b * TLEN + t0 + k) * 2 + c];

        #pragma unroll
        for (int i = 0; i < SUBL; i++) {
            float tf = (float)(t0 + i + 1);
            float inv_t = 1.0f / tf;
            hippo_step(s, inv_t, xv8[i] * inv_t);
            #pragma unroll
            for (int k = 0; k < 4; k++)
                hbuf[(row_loc + i) * 9 + ((c * 4 + k + wrot) & 7)] =
                    pkh(s[2 * k], s[2 * k + 1]);
        }
    }

    // ---- stage phase 1 (all threads; overlaps expand latency)
    {
        int i = tid >> 4, q = tid & 15;
        #pragma unroll
        for (int oo = 0; oo < 2; oo++) {
            int o = q + oo * 16;
            const float* src = ws1 + o * 208 + i * 13;
            int dst = i * 608 + o * 19;
            #pragma unroll
            for (int p = 0; p < 19; p++) {
                int j0 = (p < 10) ? (2 * p) : (2 * (p - 10) + 1);
                float lo = (j0 >= 3 && j0 <= 15) ? src[j0 - 3] : 0.0f;
                float hi = (j0 + 1 >= 3 && j0 + 1 <= 15) ? src[j0 - 2] : 0.0f;
                wldsU[dst + p] = pkh(lo, hi);
            }
        }
    }
    __syncthreads();

    // ---- layer 1: 16 -> 32 (rolled over 8 input pairs from hbuf)
    float acc1[32];
    #pragma unroll
    for (int o = 0; o < 32; o++) acc1[o] = 0.0f;

    #pragma unroll 1
    for (int pi = 0; pi < 8; pi++) {
        h2 xp = u2h(hbuf[tid * 9 + ((pi + rot) & 7)]);
        #pragma unroll
        for (int par = 0; par < 2; par++) {
            int i = 2 * pi + par;
            float xv = (par == 0) ? (float)xp.x : (float)xp.y;
            float sx = silu(xv);
            float B0, B1, B2, B3; int m;
            bspline4(xv, B0, B1, B2, B3, m);
            h2 B01 = u2h(pkh(B0, B1));
            h2 B23 = u2h(pkh(B2, B3));
            int poff = (m & 1) ? (10 + ((m - 1) >> 1)) : (m >> 1);
            int base = i * 608 + poff;
            const float* wbrow = wb1 + i;       // wb1[o*16+i]
            #pragma unroll
            for (int o = 0; o < 32; o++) {
                unsigned int da = wldsU[base + o * 19];
                unsigned int db = wldsU[base + o * 19 + 1];
                float a = acc1[o];
                a = dot2f(B01, u2h(da), a);
                a = dot2f(B23, u2h(db), a);
                a = fmaf(sx, wbrow[o * 16], a);
                acc1[o] = a;
            }
        }
    }
    // first half of layer-1 output -> own hbuf row
    #pragma unroll
    for (int op = 0; op < 8; op++)
        hbuf[tid * 9 + ((op + rot) & 7)] = pkh(acc1[2 * op], acc1[2 * op + 1]);

    __syncthreads();   // all waves done reading phase-1 weights

    // ---- stage phase 2 (affine, all threads)
    {
        int i = tid >> 3, q = tid & 7;
        #pragma unroll
        for (int oo = 0; oo < 2; oo++) {
            int o = q + oo * 8;
            const float* src = ws2 + o * 416 + i * 13;
            int dst = i * 304 + o * 19;
            #pragma unroll
            for (int p = 0; p < 19; p++) {
                int j0 = (p < 10) ? (2 * p) : (2 * (p - 10) + 1);
                float lo = (j0 >= 3 && j0 <= 15) ? src[j0 - 3] : 0.0f;
                float hi = (j0 + 1 >= 3 && j0 + 1 <= 15) ? src[j0 - 2] : 0.0f;
                wldsU[dst + p] = pkh(lo, hi);
            }
        }
    }
    __syncthreads();

    // ---- layer 2: 32 -> 16 in two input halves (acc1[16..31] in regs
    // through half 0; written to own row between halves)
    float acc2[16];
    #pragma unroll
    for (int o = 0; o < 16; o++) acc2[o] = 0.0f;

    #pragma unroll 1
    for (int half = 0; half < 2; half++) {
        #pragma unroll 1
        for (int pi = 0; pi < 8; pi++) {
            h2 yp = u2h(hbuf[tid * 9 + ((pi + rot) & 7)]);
            #pragma unroll
            for (int par = 0; par < 2; par++) {
                int i = half * 16 + 2 * pi + par;
                float yv = (par == 0) ? (float)yp.x : (float)yp.y;
                float sx = silu(yv);
                float B0, B1, B2, B3; int m;
                bspline4(yv, B0, B1, B2, B3, m);
                h2 B01 = u2h(pkh(B0, B1));
                h2 B23 = u2h(pkh(B2, B3));
                int poff = (m & 1) ? (10 + ((m - 1) >> 1)) : (m >> 1);
                int base = i * 304 + poff;
                const float* wbrow = wb2 + i;   // wb2[o*32+i]
                #pragma unroll
                for (int o = 0; o < 16; o++) {
                    unsigned int da = wldsU[base + o * 19];
                    unsigned int db = wldsU[base + o * 19 + 1];
                    float a = acc2[o];
                    a = dot2f(B01, u2h(da), a);
                    a = dot2f(B23, u2h(db), a);
                    a = fmaf(sx, wbrow[o * 32], a);
                    acc2[o] = a;
                }
            }
        }
        if (half == 0) {
            #pragma unroll
            for (int op = 0; op < 8; op++)
                hbuf[tid * 9 + ((op + rot) & 7)] =
                    pkh(acc1[16 + 2 * op], acc1[17 + 2 * op]);
        }
    }

    // ---- layer 3: 16 -> 1, fully unrolled, fp32 weights from global
    float acc3 = 0.0f;
    #pragma unroll
    for (int i = 0; i < 16; i++) {
        float xv = acc2[i];
        float sx = silu(xv);
        float B0, B1, B2, B3; int m;
        bspline4(xv, B0, B1, B2, B3, m);
        acc3 = fmaf(sx, wb3[i], acc3);
        const float* w3 = &ws3[i * 13];
        int j0 = m - 3;
        float w0v = (j0 >= 0)              ? w3[j0]     : 0.0f;
        float w1v = (j0 >= -1 && j0 <= 11) ? w3[j0 + 1] : 0.0f;
        float w2v = (j0 >= -2 && j0 <= 10) ? w3[j0 + 2] : 0.0f;
        float w3v = (j0 <= 9)              ? w3[j0 + 3] : 0.0f;
        acc3 = fmaf(B0, w0v, acc3);
        acc3 = fmaf(B1, w1v, acc3);
        acc3 = fmaf(B2, w2v, acc3);
        acc3 = fmaf(B3, w3v, acc3);
    }
    out[row] = acc3;
}

// ---------------------------------------------------------------------------
extern "C" void kernel_launch(void* const* d_in, const int* in_sizes, int n_in,
                              void* d_out, int out_size, void* d_ws, size_t ws_size,
                              hipStream_t stream) {
    const float* x_seq = (const float*)d_in[0];
    const float* wb1   = (const float*)d_in[1];
    const float* ws1   = (const float*)d_in[2];
    const float* wb2   = (const float*)d_in[3];
    const float* ws2   = (const float*)d_in[4];
    const float* wb3   = (const float*)d_in[5];
    const float* ws3   = (const float*)d_in[6];

    float* ws   = (float*)d_ws;
    float* Psub = ws;                   // 32*32*64        =   65536
    float* Vsub = ws + 65536;           // 32*32*64*8      =  524288
    float* Pfin = ws + 589824;          // 32*64           =    2048
    float* Vfin = ws + 591872;          // 32*64*8         =   16384
    float* S0   = ws + 608256;          // 32*64*8         =   16384
    float* out  = (float*)d_out;

    hipLaunchKernelGGL(hippo_chunk_kernel,   dim3(NCH), dim3(128), 0, stream,
                       x_seq, Psub, Vsub, Pfin, Vfin);
    hipLaunchKernelGGL(hippo_compose_kernel, dim3(1),   dim3(64),  0, stream,
                       Pfin, Vfin, S0);
    hipLaunchKernelGGL(kan_kernel, dim3(NROWS / 256), dim3(256), 0, stream,
                       x_seq, Psub, Vsub, S0,
                       wb1, ws1, wb2, ws2, wb3, ws3, out);
}